// Round 4
// baseline (137.329 us; speedup 1.0000x reference)
//
#include <hip/hip_runtime.h>

#define N_BATCH   50000
#define N_FEATURE 128
#define DEPTH     9
#define N_TREE    200
#define N_NODE    1023
#define N_OUTPUT  8

#define BPB     64                            // batches per block (lanes)
#define WAVES   8
#define BLOCK   (WAVES * 64)                  // 512 threads
#define DUALS   12                            // 12 dual rounds (16 trees) + 1 single (8)

// ILP=2: each wave traverses TWO independent trees per round -> 8 chains/SIMD
// at 2 blocks/CU (LDS 72KB). Grid: 512 full chunk-blocks (2/CU x 256) + 270
// surplus chunks split into 2 half-blocks each (rounds 0-5 / 6-12) -> ~1.53
// generations, the packing lower bound at this occupancy.
#define FULL_CHUNKS 512
#define NCHUNK      ((N_BATCH + BPB - 1) / BPB)     // 782
#define TAIL_CHUNKS (NCHUNK - FULL_CHUNKS)          // 270
#define TAIL_BLOCKS (TAIL_CHUNKS * 2)               // 540
#define GRID        (FULL_CHUNKS + TAIL_BLOCKS)     // 1052

// Per-wave-per-tree buffer: shifted heap copy (proven layout)
//   thS[k] = th[k+1] (k=0..511)   [2048 B]   pair(n) = float2 @ thS[2n]
//   fS[k]  = feat[k+1] u8         [512 B]    fpair(n) = u16 @ fS[2n]
// Quad staging: lane q holds nodes 4q+1..4q+4 -> ds_write_b128 + packed b32.
// Root th/feat via uniform vector load; root children via readlane(lane 0).
#define TREE_B  2560
#define REC_B   (WAVES * 2 * TREE_B)          // 40960

#define BOFF    ((size_t)8 * N_NODE)                    // set-B elem offset
#define VBOFF   ((size_t)8 * N_NODE * N_OUTPUT)         // set-B value offset

__device__ __forceinline__ float readlane_f(float v, int lane) {
    return __int_as_float(__builtin_amdgcn_readlane(__float_as_int(v), lane));
}
__device__ __forceinline__ unsigned pack4(int4 f) {
    return (f.x & 255) | ((f.y & 255) << 8) | ((f.z & 255) << 16) | ((unsigned)f.w << 24);
}

__global__ __launch_bounds__(BLOCK, 4)        // 4 waves/EU -> 2 blocks/CU, 16 waves/CU
void tree_kernel(const float* __restrict__ x,
                 const int*   __restrict__ feature,
                 const float* __restrict__ threshold,
                 const float* __restrict__ value,
                 float*       __restrict__ out)
{
    __shared__ float xt[N_FEATURE * BPB];           // 32 KB, xt[f*64+b]: bank = lane%32 (free)
    __shared__ __align__(16) char recbuf[REC_B];    // 40 KB, 16 tree slices (2 per wave)

    const int tid = threadIdx.x;
    const int bid = blockIdx.x;
    const int b   = tid & 63;                       // lane = batch within chunk
    const int g   = tid >> 6;                       // wave id
    char* wbufA = recbuf + (2 * g)     * TREE_B;
    char* wbufB = recbuf + (2 * g + 1) * TREE_B;

    int chunk, rA, rB; bool single, tail;
    if (bid < FULL_CHUNKS) { chunk = bid; rA = 0; rB = DUALS; single = true; tail = false; }
    else {
        const int t2 = bid - FULL_CHUNKS;
        chunk = FULL_CHUNKS + (t2 >> 1);
        if (t2 & 1) { rA = 6; rB = DUALS; single = true; }
        else        { rA = 0; rB = 6;     single = false; }
        tail = true;
    }

    // set-A tree pointers (tree 16*r + g); set B = A + 8 trees (constant offset)
    const float* trowA = threshold + (size_t)(rA * 16 + g) * N_NODE;
    const int*   frowA = feature   + (size_t)(rA * 16 + g) * N_NODE;
    const float* vbaseA = value + (size_t)(rA * 16 + g) * (N_NODE * N_OUTPUT);
    const float* tqA = trowA + 1 + 4 * b;           // nodes 4b+1..4b+4
    const int*   fqA = frowA + 1 + 4 * b;

    // ---- prime prefetch: both trees of round rA (every block has >=6 duals) ----
    float4 ta0, ta1, tb0, tb1; int4 fa0, fa1, fb0, fb1;
    __builtin_memcpy(&ta0, tqA,        16);
    __builtin_memcpy(&ta1, tqA + 256,  16);
    __builtin_memcpy(&fa0, fqA,        16);
    __builtin_memcpy(&fa1, fqA + 256,  16);
    __builtin_memcpy(&tb0, tqA + BOFF,       16);
    __builtin_memcpy(&tb1, tqA + BOFF + 256, 16);
    __builtin_memcpy(&fb0, fqA + BOFF,       16);
    __builtin_memcpy(&fb1, fqA + BOFF + 256, 16);
    float th0a = trowA[0];          int f0a = frowA[0];
    float th0b = trowA[BOFF];       int f0b = frowA[BOFF];

    // ---- stage x chunk transposed into LDS (conflict-free via XOR-swizzled R) ----
    {
        const float4* x4 = (const float4*)x;
        float4* R = (float4*)recbuf;                // 16 KB alias (pre-round only)
        #pragma unroll
        for (int rr = 0; rr < 2; ++rr) {
            #pragma unroll
            for (int k = 0; k < 2; ++k) {           // 1024 float4 / 512 thr = 2 iters
                const int j  = tid + k * BLOCK;
                const int bl = j >> 5, f4 = j & 31;
                const int gb = chunk * BPB + rr * 32 + bl;
                float4 v = (gb < N_BATCH) ? x4[(size_t)gb * 32 + f4]
                                          : make_float4(0.f, 0.f, 0.f, 0.f);
                R[bl * 32 + (f4 ^ bl)] = v;
            }
            __syncthreads();
            {
                const int b32 = tid & 31, fc = tid >> 5;   // fc = 0..15
                const int bb = rr * 32 + b32;
                #pragma unroll
                for (int c = 0; c < 2; ++c) {
                    const int f4 = fc * 2 + c;
                    float4 v = R[b32 * 32 + (f4 ^ b32)];
                    xt[(f4 * 4 + 0) * BPB + bb] = v.x;
                    xt[(f4 * 4 + 1) * BPB + bb] = v.y;
                    xt[(f4 * 4 + 2) * BPB + bb] = v.z;
                    xt[(f4 * 4 + 3) * BPB + bb] = v.w;
                }
            }
            __syncthreads();
        }
    }
    // No block barriers until the final reduction: each wave owns its two tree
    // slices exclusively; per-wave DS program order provides WAR/RAW safety.

    float acc[N_OUTPUT];
    #pragma unroll
    for (int o = 0; o < N_OUTPUT; ++o) acc[o] = 0.f;
    float4 vpa0 = make_float4(0.f,0.f,0.f,0.f), vpa1 = vpa0;  // leaf pipelines
    float4 vpb0 = vpa0, vpb1 = vpa0;

    float*         thSA = (float*)wbufA;
    unsigned char* fSA  = (unsigned char*)(wbufA + 2048);
    float*         thSB = (float*)wbufB;
    unsigned char* fSB  = (unsigned char*)(wbufB + 2048);

    for (int r = rA; r < rB; ++r) {
        // ---- stage both trees: 2x (2 ds_write_b128 + 2 ds_write_b32) ----
        ((float4*)thSA)[b]      = ta0;
        ((float4*)thSA)[b + 64] = ta1;
        ((unsigned*)fSA)[b]      = pack4(fa0);
        ((unsigned*)fSA)[b + 64] = pack4(fa1);
        ((float4*)thSB)[b]      = tb0;
        ((float4*)thSB)[b + 64] = tb1;
        ((unsigned*)fSB)[b]      = pack4(fb0);
        ((unsigned*)fSB)[b + 64] = pack4(fb1);

        // ---- roots + root children from registers ----
        const float th0ac = th0a; const int f0ac = f0a;
        const float th0bc = th0b; const int f0bc = f0b;
        const float cxa = readlane_f(ta0.x, 0), cya = readlane_f(ta0.y, 0);
        const int   fla0 = __builtin_amdgcn_readlane(fa0.x, 0);
        const int   fha0 = __builtin_amdgcn_readlane(fa0.y, 0);
        const float cxb = readlane_f(tb0.x, 0), cyb = readlane_f(tb0.y, 0);
        const int   flb0 = __builtin_amdgcn_readlane(fb0.x, 0);
        const int   fhb0 = __builtin_amdgcn_readlane(fb0.y, 0);

        // ---- prefetch next round (A also feeds the trailing single round) ----
        const bool pfA = (r + 1 < rB) || (single && r + 1 == rB);
        if (pfA) {
            trowA += (size_t)16 * N_NODE; frowA += (size_t)16 * N_NODE;
            tqA   += (size_t)16 * N_NODE; fqA   += (size_t)16 * N_NODE;
            __builtin_memcpy(&ta0, tqA,       16);
            __builtin_memcpy(&ta1, tqA + 256, 16);
            __builtin_memcpy(&fa0, fqA,       16);
            __builtin_memcpy(&fa1, fqA + 256, 16);
            th0a = trowA[0]; f0a = frowA[0];
            if (r + 1 < rB) {                       // set B only if a next dual exists
                __builtin_memcpy(&tb0, tqA + BOFF,       16);
                __builtin_memcpy(&tb1, tqA + BOFF + 256, 16);
                __builtin_memcpy(&fb0, fqA + BOFF,       16);
                __builtin_memcpy(&fb1, fqA + BOFF + 256, 16);
                th0b = trowA[BOFF]; f0b = frowA[BOFF];
            }
        }

        // ---- traverse both trees, interleaved independent chains ----
        int   mA = 1,        mB = 1;
        float thA = th0ac,   thB = th0bc;
        int   fvA = f0ac,    fvB = f0bc;
        float2 cA = make_float2(cxa, cya), cB = make_float2(cxb, cyb);
        int   flA = fla0, fhA = fha0, flB = flb0, fhB = fhb0;
        #pragma unroll
        for (int d = 0; d < DEPTH; ++d) {
            const float xvA = xt[fvA * BPB + b];
            const float xvB = xt[fvB * BPB + b];
            const int sA = (xvA > thA) ? 1 : 0;
            const int sB = (xvB > thB) ? 1 : 0;
            mA = 2 * mA + sA;
            mB = 2 * mB + sB;
            if (d < DEPTH - 1) {
                thA = sA ? cA.y : cA.x;  fvA = sA ? fhA : flA;
                thB = sB ? cB.y : cB.x;  fvB = sB ? fhB : flB;
            }
            if (d < DEPTH - 2) {                    // speculative pair reads
                cA = ((float2*)thSA)[mA - 1];
                const int k2A = ((unsigned short*)fSA)[mA - 1];
                flA = k2A & 255; fhA = k2A >> 8;
                cB = ((float2*)thSB)[mB - 1];
                const int k2B = ((unsigned short*)fSB)[mB - 1];
                flB = k2B & 255; fhB = k2B >> 8;
            }
        }
        // ---- accumulate previous round's leaves (A then B: canonical order) ----
        acc[0] += vpa0.x; acc[1] += vpa0.y; acc[2] += vpa0.z; acc[3] += vpa0.w;
        acc[4] += vpa1.x; acc[5] += vpa1.y; acc[6] += vpa1.z; acc[7] += vpa1.w;
        acc[0] += vpb0.x; acc[1] += vpb0.y; acc[2] += vpb0.z; acc[3] += vpb0.w;
        acc[4] += vpb1.x; acc[5] += vpb1.y; acc[6] += vpb1.z; acc[7] += vpb1.w;
        {
            const float4* vA = (const float4*)(vbaseA + (size_t)(mA - 1) * N_OUTPUT);
            const float4* vB = (const float4*)(vbaseA + VBOFF + (size_t)(mB - 1) * N_OUTPUT);
            vpa0 = vA[0]; vpa1 = vA[1];
            vpb0 = vB[0]; vpb1 = vB[1];
        }
        vbaseA += (size_t)16 * N_NODE * N_OUTPUT;
    }

    if (single) {
        // ---- trailing single round: tree 192+g, set-A regs already prefetched ----
        ((float4*)thSA)[b]      = ta0;
        ((float4*)thSA)[b + 64] = ta1;
        ((unsigned*)fSA)[b]      = pack4(fa0);
        ((unsigned*)fSA)[b + 64] = pack4(fa1);
        const float cxa = readlane_f(ta0.x, 0), cya = readlane_f(ta0.y, 0);
        const int   fla0 = __builtin_amdgcn_readlane(fa0.x, 0);
        const int   fha0 = __builtin_amdgcn_readlane(fa0.y, 0);

        int   m  = 1;
        float th = th0a;
        int   fv = f0a;
        float2 c = make_float2(cxa, cya);
        int   fl = fla0, fh = fha0;
        #pragma unroll
        for (int d = 0; d < DEPTH; ++d) {
            const float xv = xt[fv * BPB + b];
            const int s = (xv > th) ? 1 : 0;
            m = 2 * m + s;
            if (d < DEPTH - 1) { th = s ? c.y : c.x; fv = s ? fh : fl; }
            if (d < DEPTH - 2) {
                c = ((float2*)thSA)[m - 1];
                const int k2 = ((unsigned short*)fSA)[m - 1];
                fl = k2 & 255; fh = k2 >> 8;
            }
        }
        // accumulate last dual's leaves, then pipeline the single leaf
        acc[0] += vpa0.x; acc[1] += vpa0.y; acc[2] += vpa0.z; acc[3] += vpa0.w;
        acc[4] += vpa1.x; acc[5] += vpa1.y; acc[6] += vpa1.z; acc[7] += vpa1.w;
        acc[0] += vpb0.x; acc[1] += vpb0.y; acc[2] += vpb0.z; acc[3] += vpb0.w;
        acc[4] += vpb1.x; acc[5] += vpb1.y; acc[6] += vpb1.z; acc[7] += vpb1.w;
        {
            const float4* vA = (const float4*)(vbaseA + (size_t)(m - 1) * N_OUTPUT);
            vpa0 = vA[0]; vpa1 = vA[1];
        }
        vpb0 = make_float4(0.f,0.f,0.f,0.f); vpb1 = vpb0;
    }
    // drain leaf pipelines (canonical order: ... , 184+g, 192+g)
    acc[0] += vpa0.x; acc[1] += vpa0.y; acc[2] += vpa0.z; acc[3] += vpa0.w;
    acc[4] += vpa1.x; acc[5] += vpa1.y; acc[6] += vpa1.z; acc[7] += vpa1.w;
    acc[0] += vpb0.x; acc[1] += vpb0.y; acc[2] += vpb0.z; acc[3] += vpb0.w;
    acc[4] += vpb1.x; acc[5] += vpb1.y; acc[6] += vpb1.z; acc[7] += vpb1.w;

    // ---- reduce 8 waves' partials (alias recbuf, stride-9 pad) ----
    __syncthreads();
    float* red = (float*)recbuf;                    // 8*576*4 = 18432 <= 40960
    {
        float* dst = red + (g * 576 + b * 9);
        #pragma unroll
        for (int o = 0; o < N_OUTPUT; ++o) dst[o] = acc[o];
    }
    __syncthreads();
    {
        const int bl = tid >> 3, o = tid & 7;       // 512 threads = 64 batches x 8 outs
        const int bg = chunk * BPB + bl;
        float s = 0.f;
        #pragma unroll
        for (int gg = 0; gg < WAVES; ++gg) s += red[gg * 576 + bl * 9 + o];
        s *= (1.0f / N_TREE);
        if (!tail) {
            out[(size_t)chunk * (BPB * N_OUTPUT) + tid] = s;   // coalesced, exactly once
        } else if (bg < N_BATCH) {
            atomicAdd(out + (size_t)bg * N_OUTPUT + o, s);
        }
    }
}

extern "C" void kernel_launch(void* const* d_in, const int* in_sizes, int n_in,
                              void* d_out, int out_size, void* d_ws, size_t ws_size,
                              hipStream_t stream) {
    const float* x         = (const float*)d_in[0];
    const int*   feature   = (const int*)d_in[1];
    const float* threshold = (const float*)d_in[2];
    const float* value     = (const float*)d_in[5];   // children implied by complete heap layout
    float* out = (float*)d_out;

    // zero the tail-chunk region (atomic accumulation); ~551 KB
    const size_t tail_off = (size_t)FULL_CHUNKS * BPB * N_OUTPUT;
    if ((size_t)out_size > tail_off) {
        hipMemsetAsync(out + tail_off, 0, ((size_t)out_size - tail_off) * sizeof(float), stream);
    }

    tree_kernel<<<dim3(GRID), dim3(BLOCK), 0, stream>>>(x, feature, threshold, value, out);
}